// Round 3
// baseline (4052.473 us; speedup 1.0000x reference)
//
#include <hip/hip_runtime.h>

#define B_    32
#define CIN_  96
#define EXC_  102
#define INH_  26
#define HH    64
#define WW    64
#define HW_   4096
#define NPOS  (B_*HW_)   // 131072

__device__ __forceinline__ int refl(int i) {
    if (i < 0) i = -i;
    if (i > 63) i = 126 - i;
    return i;
}

// ---------------------------------------------------------------------------
// Direct 5x5 conv, reflect padding. Block tile = 16 rows x 64 cols, 256 thr,
// thread = 1 row x 4 px x TE channels. Staging offsets precomputed once;
// double-buffered LDS, one barrier/channel, global loads prefetched.
// Weights are wave-uniform -> s_load (scalar pipe). addin may alias out.
// ---------------------------------------------------------------------------
template<int CIN, int TE>
__global__ __launch_bounds__(256, 4) void conv5x5_v3(
    const float* __restrict__ in, const float* __restrict__ wgt,
    const float* __restrict__ addin, float* __restrict__ out,
    int Cout, int do_relu)
{
    __shared__ __align__(16) float sx[2][20*68];
    const int t  = threadIdx.x;
    const int h0 = blockIdx.x * 16;
    const int e0 = blockIdx.y * TE;
    const int b  = blockIdx.z;
    const int r  = t >> 4;                 // 0..15 output row in tile
    const int cg = (t & 15) * 4;           // output col group (4 px)

    // staging: 20 rows x 68 cols = 1360 words, slot offsets fixed per thread
    int goff[6];
#pragma unroll
    for (int s = 0; s < 6; ++s) {
        int i = t + 256*s;
        if (i < 1360) {
            int lh = i / 68, lw = i - lh*68;
            goff[s] = refl(h0 - 2 + lh)*WW + refl(lw - 2);
        } else goff[s] = 0;
    }

    float acc[TE][4];
#pragma unroll
    for (int e = 0; e < TE; ++e)
#pragma unroll
        for (int j = 0; j < 4; ++j) acc[e][j] = 0.f;

    const float* inb = in + (size_t)b*CIN*HW_;

    float pre[6];
#pragma unroll
    for (int s = 0; s < 6; ++s) { int i = t + 256*s; if (i < 1360) pre[s] = inb[goff[s]]; }
#pragma unroll
    for (int s = 0; s < 6; ++s) { int i = t + 256*s; if (i < 1360) sx[0][i] = pre[s]; }

    int buf = 0;
    for (int c = 0; c < CIN; ++c) {
        __syncthreads();
        if (c + 1 < CIN) {
            const float* incn = inb + (size_t)(c+1)*HW_;
#pragma unroll
            for (int s = 0; s < 6; ++s) { int i = t + 256*s; if (i < 1360) pre[s] = incn[goff[s]]; }
        }
        const float* sb = sx[buf];
#pragma unroll
        for (int kh = 0; kh < 5; ++kh) {
            const float4* rowp = (const float4*)(sb + (r + kh)*68 + cg);
            float4 v0 = rowp[0], v1 = rowp[1];
            float xv[8] = {v0.x, v0.y, v0.z, v0.w, v1.x, v1.y, v1.z, v1.w};
#pragma unroll
            for (int kw = 0; kw < 5; ++kw) {
#pragma unroll
                for (int e = 0; e < TE; ++e) {
                    int ee = e0 + e; if (ee >= Cout) ee = Cout - 1;   // uniform clamp
                    float wv = wgt[((size_t)ee*CIN + c)*25 + kh*5 + kw];
#pragma unroll
                    for (int j = 0; j < 4; ++j)
                        acc[e][j] = fmaf(xv[kw + j], wv, acc[e][j]);
                }
            }
        }
        if (c + 1 < CIN) {
#pragma unroll
            for (int s = 0; s < 6; ++s) { int i = t + 256*s; if (i < 1360) sx[buf^1][i] = pre[s]; }
        }
        buf ^= 1;
    }

    const int h = h0 + r;
#pragma unroll
    for (int e = 0; e < TE; ++e) {
        if (e0 + e < Cout) {
            size_t oidx = ((size_t)(b*Cout + e0 + e))*HW_ + h*WW + cg;
            float4 v = make_float4(acc[e][0], acc[e][1], acc[e][2], acc[e][3]);
            if (do_relu) {
                v.x = fmaxf(v.x, 0.f); v.y = fmaxf(v.y, 0.f);
                v.z = fmaxf(v.z, 0.f); v.w = fmaxf(v.w, 0.f);
            }
            if (addin) {
                const float4 a = *(const float4*)(addin + oidx);
                v.x += a.x; v.y += a.y; v.z += a.z; v.w += a.w;
            }
            *(float4*)(out + oidx) = v;
        }
    }
}

// Depthwise 5x5 surround-modulation conv, ZERO padding. 32x32 tile, TW=4.
__global__ __launch_bounds__(256) void smconv_v2(
    const float* __restrict__ in, const float* __restrict__ sm,
    float* __restrict__ out)
{
    __shared__ __align__(16) float sx[36*36];
    const int tid = threadIdx.x;
    const int tile = blockIdx.x;
    const int e = blockIdx.y;
    const int b = blockIdx.z;
    const int h0 = (tile >> 1) * 32, w0 = (tile & 1) * 32;
    const int r  = tid >> 3;
    const int cg = (tid & 7) * 4;
    const float* inc = in + ((size_t)(b*EXC_ + e))*HW_;
#pragma unroll
    for (int it = 0; it < 6; ++it) {
        int i = tid + it*256;
        if (i < 1296) {
            int lh = i / 36, lw = i - lh*36;
            int gh = h0 - 2 + lh, gw = w0 - 2 + lw;
            float v = 0.f;
            if (gh >= 0 && gh < HH && gw >= 0 && gw < WW) v = inc[gh*WW + gw];
            sx[i] = v;
        }
    }
    __syncthreads();
    float a0 = 0.f, a1 = 0.f, a2 = 0.f, a3 = 0.f;
#pragma unroll
    for (int kh = 0; kh < 5; ++kh) {
        const float4* rowp = (const float4*)(sx + (r + kh)*36 + cg);
        float4 v0 = rowp[0], v1 = rowp[1];
        float xv[8] = {v0.x, v0.y, v0.z, v0.w, v1.x, v1.y, v1.z, v1.w};
#pragma unroll
        for (int kw = 0; kw < 5; ++kw) {
            float wv = sm[kh*5 + kw];
            a0 = fmaf(xv[kw+0], wv, a0);
            a1 = fmaf(xv[kw+1], wv, a1);
            a2 = fmaf(xv[kw+2], wv, a2);
            a3 = fmaf(xv[kw+3], wv, a3);
        }
    }
    size_t oidx = ((size_t)(b*EXC_ + e))*HW_ + (h0 + r)*WW + w0 + cg;
    *(float4*)(out + oidx) = make_float4(a0, a1, a2, a3);
}

// Per-pixel channel argmax (first-occurrence on strict >, matching np.argmax).
__global__ void wta_kernel(const float* __restrict__ in, int* __restrict__ win,
                           float* __restrict__ val, int C, int use_abs)
{
    int p = blockIdx.x*256 + threadIdx.x;   // 0..NPOS-1
    int b = p >> 12, hw = p & 4095;
    const float* base = in + ((size_t)b*C)*HW_ + hw;
    float bestv = base[0];
    float bestk = use_abs ? fabsf(bestv) : bestv;
    int besti = 0;
    for (int c = 1; c < C; ++c) {
        float v = base[(size_t)c*HW_];
        float key = use_abs ? fabsf(v) : v;
        if (key > bestk) { bestk = key; bestv = v; besti = c; }
    }
    win[p] = besti;
    val[p] = bestv;
}

// yx_ee[e,c] = sum_p [win_e==e] val_e * x[b,c,p];  yu_e[e] = sum val_e
__global__ __launch_bounds__(256) void scatter_ee_kernel(
    const float* __restrict__ x, const int* __restrict__ win_e,
    const float* __restrict__ val_e, float* __restrict__ yx_ee,
    float* __restrict__ yu_e)
{
    __shared__ float s_yx[EXC_*CIN_];   // 9792 floats
    __shared__ float s_yu[EXC_];
    for (int i = threadIdx.x; i < EXC_*CIN_; i += 256) s_yx[i] = 0.f;
    if (threadIdx.x < EXC_) s_yu[threadIdx.x] = 0.f;
    __syncthreads();
    int p0 = blockIdx.x * 512;          // 256 blocks x 512 positions
    for (int it = 0; it < 2; ++it) {
        int p = p0 + it*256 + threadIdx.x;
        int b = p >> 12, hw = p & 4095;
        int wi = win_e[p]; float v = val_e[p];
        atomicAdd(&s_yu[wi], v);
        const float* xb = x + ((size_t)b*CIN_)*HW_ + hw;
        float* row = s_yx + wi*CIN_;
        for (int c = 0; c < CIN_; ++c)
            atomicAdd(&row[c], v * xb[(size_t)c*HW_]);
    }
    __syncthreads();
    for (int i = threadIdx.x; i < EXC_*CIN_; i += 256) atomicAdd(&yx_ee[i], s_yx[i]);
    if (threadIdx.x < EXC_) atomicAdd(&yu_e[threadIdx.x], s_yu[threadIdx.x]);
}

// yx_ei[i,e] += val_e*val_i at (win_i,win_e);  yu_i[i] += |val_i|
__global__ __launch_bounds__(256) void scatter_ei_kernel(
    const int* __restrict__ win_e, const float* __restrict__ val_e,
    const int* __restrict__ win_i, const float* __restrict__ val_i,
    float* __restrict__ yx_ei, float* __restrict__ yu_i)
{
    __shared__ float s[INH_*EXC_ + INH_];  // 2652 + 26
    for (int i = threadIdx.x; i < INH_*EXC_ + INH_; i += 256) s[i] = 0.f;
    __syncthreads();
    int p0 = blockIdx.x * 1024;            // 128 blocks x 1024 positions
    for (int it = 0; it < 4; ++it) {
        int p = p0 + it*256 + threadIdx.x;
        int we = win_e[p]; float ve = val_e[p];
        int wi = win_i[p]; float vi = val_i[p];
        atomicAdd(&s[wi*EXC_ + we], ve*vi);
        atomicAdd(&s[INH_*EXC_ + wi], fabsf(vi));
    }
    __syncthreads();
    for (int i = threadIdx.x; i < INH_*EXC_ + INH_; i += 256) {
        float v = s[i];
        if (v != 0.f) {
            if (i < INH_*EXC_) atomicAdd(&yx_ei[i], v);
            else               atomicAdd(&yu_i[i - INH_*EXC_], v);
        }
    }
}

// yx_ie[e,i] = sum_p [win_i==i] val_i * y[b,e,p]
__global__ __launch_bounds__(256) void scatter_ie_kernel(
    const float* __restrict__ y, const int* __restrict__ win_i,
    const float* __restrict__ val_i, float* __restrict__ yx_ie)
{
    __shared__ float s[EXC_*INH_];  // 2652
    for (int i = threadIdx.x; i < EXC_*INH_; i += 256) s[i] = 0.f;
    __syncthreads();
    int p0 = blockIdx.x * 512;      // 256 blocks x 512 positions
    for (int it = 0; it < 2; ++it) {
        int p = p0 + it*256 + threadIdx.x;
        int b = p >> 12, hw = p & 4095;
        int wi = win_i[p]; float v = val_i[p];
        if (v != 0.f) {
            const float* yb = y + ((size_t)b*EXC_)*HW_ + hw;
            for (int e = 0; e < EXC_; ++e)
                atomicAdd(&s[e*INH_ + wi], v * yb[(size_t)e*HW_]);
        }
    }
    __syncthreads();
    for (int i = threadIdx.x; i < EXC_*INH_; i += 256) atomicAdd(&yx_ie[i], s[i]);
}

// absmax of upd = yx - yu[e]*w  (nonneg float bits are int-monotonic)
__global__ void upd_absmax_kernel(const float* __restrict__ yx,
    const float* __restrict__ yu, const float* __restrict__ w,
    int E, int C, unsigned int* __restrict__ amax)
{
    __shared__ unsigned int sm_;
    if (threadIdx.x == 0) sm_ = 0u;
    __syncthreads();
    int n = E*C*25;
    float m = 0.f;
    for (int idx = blockIdx.x*256 + threadIdx.x; idx < n; idx += gridDim.x*256) {
        int ec = idx / 25;
        int e = ec / C;
        float v = yx[ec] - yu[e]*w[idx];
        m = fmaxf(m, fabsf(v));
    }
    atomicMax(&sm_, __float_as_uint(m));
    __syncthreads();
    if (threadIdx.x == 0) atomicMax(amax, sm_);
}

__global__ void upd_write_kernel(const float* __restrict__ yx,
    const float* __restrict__ yu, const float* __restrict__ w,
    int E, int C, const unsigned int* __restrict__ amax,
    float* __restrict__ out)
{
    int n = E*C*25;
    int idx = blockIdx.x*256 + threadIdx.x;
    if (idx >= n) return;
    int ec = idx / 25;
    int e = ec / C;
    float v = yx[ec] - yu[e]*w[idx];
    float mx = __uint_as_float(*amax);
    out[idx] = v / (mx + 1e-8f);
}

extern "C" void kernel_launch(void* const* d_in, const int* in_sizes, int n_in,
                              void* d_out, int out_size, void* d_ws, size_t ws_size,
                              hipStream_t stream)
{
    const float* x    = (const float*)d_in[0];
    const float* w_ee = (const float*)d_in[1];
    const float* w_ei = (const float*)d_in[2];
    const float* w_ie = (const float*)d_in[3];
    const float* smk  = (const float*)d_in[4];
    float* out = (float*)d_out;

    // workspace layout (floats)
    float* ws    = (float*)d_ws;
    float* y_e   = ws;                                   // B*EXC*HW (reused as y_pre in place)
    float* y_i   = y_e + (size_t)B_*EXC_*HW_;            // B*INH*HW
    int*   win_e = (int*)(y_i + (size_t)B_*INH_*HW_);
    float* val_e = (float*)(win_e + NPOS);
    int*   win_i = (int*)(val_e + NPOS);
    float* val_i = (float*)(win_i + NPOS);
    float* yx_ee = val_i + NPOS;                         // 9792
    float* yx_ei = yx_ee + EXC_*CIN_;                    // 2652
    float* yx_ie = yx_ei + INH_*EXC_;                    // 2652
    float* yu_e  = yx_ie + EXC_*INH_;                    // 102
    float* yu_i  = yu_e + EXC_;                          // 26
    unsigned int* amax = (unsigned int*)(yu_i + INH_);   // 3

    hipMemsetAsync(yx_ee, 0,
        (size_t)(EXC_*CIN_ + INH_*EXC_ + EXC_*INH_ + EXC_ + INH_ + 3)*sizeof(float),
        stream);

    // y_e = conv(x, w_ee), reflect pad             [TE=12, 9 e-groups]
    conv5x5_v3<CIN_,12><<<dim3(4,9,B_), 256, 0, stream>>>(x, w_ee, nullptr, y_e, EXC_, 0);
    // WTA over excitatory channels (plain max)
    wta_kernel<<<NPOS/256, 256, 0, stream>>>(y_e, win_e, val_e, EXC_, 0);
    // y_i = relu(conv(y_e, w_ei)), reflect pad     [TE=7, 4 e-groups]
    conv5x5_v3<EXC_,7><<<dim3(4,4,B_), 256, 0, stream>>>(y_e, w_ei, nullptr, y_i, INH_, 1);
    // WTA over inhibitory channels (abs max, signed value kept)
    wta_kernel<<<NPOS/256, 256, 0, stream>>>(y_i, win_i, val_i, INH_, 1);
    // y_pre = y_e + conv(y_i, w_ie), reflect pad (in place over y_e)
    conv5x5_v3<INH_,12><<<dim3(4,9,B_), 256, 0, stream>>>(y_i, w_ie, y_e, y_e, EXC_, 0);
    // y = depthwise sm conv (zero pad) -> d_out chunk 0
    smconv_v2<<<dim3(4,EXC_,B_), 256, 0, stream>>>(y_e, smk, out);

    // Hebbian scatters
    scatter_ee_kernel<<<256, 256, 0, stream>>>(x, win_e, val_e, yx_ee, yu_e);
    scatter_ei_kernel<<<128, 256, 0, stream>>>(win_e, val_e, win_i, val_i, yx_ei, yu_i);
    scatter_ie_kernel<<<256, 256, 0, stream>>>(out, win_i, val_i, yx_ie);

    // upd normalization
    upd_absmax_kernel<<<240, 256, 0, stream>>>(yx_ee, yu_e, w_ee, EXC_, CIN_, amax+0);
    upd_absmax_kernel<<<240, 256, 0, stream>>>(yx_ei, yu_i, w_ei, INH_, EXC_, amax+1);
    upd_absmax_kernel<<<240, 256, 0, stream>>>(yx_ie, yu_e, w_ie, EXC_, INH_, amax+2);

    float* out_ee = out + (size_t)B_*EXC_*HW_;
    float* out_ei = out_ee + EXC_*CIN_*25;
    float* out_ie = out_ei + INH_*EXC_*25;
    upd_write_kernel<<<(EXC_*CIN_*25+255)/256, 256, 0, stream>>>(yx_ee, yu_e, w_ee, EXC_, CIN_, amax+0, out_ee);
    upd_write_kernel<<<(INH_*EXC_*25+255)/256, 256, 0, stream>>>(yx_ei, yu_i, w_ei, INH_, EXC_, amax+1, out_ei);
    upd_write_kernel<<<(EXC_*INH_*25+255)/256, 256, 0, stream>>>(yx_ie, yu_e, w_ie, EXC_, INH_, amax+2, out_ie);
}

// Round 4
// 593.036 us; speedup vs baseline: 6.8334x; 6.8334x over previous
//
#include <hip/hip_runtime.h>

#define B_    32
#define CIN_  96
#define EXC_  102
#define INH_  26
#define HH    64
#define WW    64
#define HW_   4096
#define NPOS  (B_*HW_)   // 131072

typedef short bf8 __attribute__((ext_vector_type(8)));
typedef float f32x4 __attribute__((ext_vector_type(4)));

__device__ __forceinline__ int refl(int i) {
    if (i < 0) i = -i;
    if (i > 63) i = 126 - i;
    return i;
}

__device__ __forceinline__ short f2bf(float f) {
    unsigned u = __float_as_uint(f);
    return (short)((u + 0x7fffu + ((u >> 16) & 1u)) >> 16);
}

// ---------------------------------------------------------------------------
// NCHW fp32 -> NHWC bf16 pack (channels padded to CPAD with zeros)
// ---------------------------------------------------------------------------
template<int C, int CPAD>
__global__ __launch_bounds__(256) void pack_nhwc(
    const float* __restrict__ src, short* __restrict__ dst)
{
    const int b = blockIdx.z;
    const int pos = blockIdx.x*64 + (threadIdx.x & 63);
    const int cg0 = threadIdx.x >> 6;
    for (int cg = cg0; cg < CPAD/8; cg += 4) {
        bf8 v;
#pragma unroll
        for (int j = 0; j < 8; ++j) {
            int c = cg*8 + j;
            float f = (c < C) ? src[((size_t)b*C + c)*HW_ + pos] : 0.f;
            v[j] = f2bf(f);
        }
        *(bf8*)(&dst[((size_t)b*HW_ + pos)*CPAD + cg*8]) = v;
    }
}

// weights [N][C][5][5] fp32 -> [tap 25][NPAD][CPAD] bf16 (zero padded)
template<int N, int C, int NPAD, int CPAD>
__global__ void pack_w(const float* __restrict__ src, short* __restrict__ dst)
{
    int idx = blockIdx.x*256 + threadIdx.x;
    if (idx >= 25*NPAD*CPAD) return;
    int tap = idx / (NPAD*CPAD);
    int rem = idx - tap*NPAD*CPAD;
    int n = rem / CPAD, c = rem - n*CPAD;
    float f = (n < N && c < C) ? src[((size_t)n*C + c)*25 + tap] : 0.f;
    dst[idx] = f2bf(f);
}

// ---------------------------------------------------------------------------
// MFMA implicit-GEMM 5x5 conv, reflect pad. Block = 16x16 spatial tile,
// 256 thr = 4 waves; wave = 4 Mtiles(rows) x NT Ntiles(16 ch each).
// A (input) staged per 32-cin chunk in LDS (records: 32 bf16 + pad, 80 B
// stride, 16B aligned); B (weights) read from global (L1-resident slices).
// ---------------------------------------------------------------------------
template<int CPAD, int NPAD, int NT, int COUT, int NCHUNK, bool RELU, bool ADDIN>
__global__ __launch_bounds__(256, 2) void conv_mfma(
    const short* __restrict__ src, const short* __restrict__ wgt,
    const float* __restrict__ addin, float* __restrict__ out)
{
    __shared__ __align__(16) short sA[400*40];
    const int t  = threadIdx.x;
    const int bx = blockIdx.x;
    const int b  = blockIdx.z;
    const int h0 = (bx >> 2) * 16;
    const int w0 = (bx &  3) * 16;
    const int lane = t & 63;
    const int wv = t >> 6;
    const int nh = lane & 15;
    const int q  = lane >> 4;

    // staging slot offsets (fixed): 400 records x 4 segs of 16B = 1600 slots
    int goff[7], loff[7];
#pragma unroll
    for (int s = 0; s < 7; ++s) {
        int i = t + 256*s;
        if (i < 1600) {
            int rec = i >> 2, seg = i & 3;
            int lh = rec / 20, lw = rec - lh*20;
            int gh = refl(h0 - 2 + lh), gw = refl(w0 - 2 + lw);
            goff[s] = (b*HW_ + gh*WW + gw) * CPAD + seg*8;
            loff[s] = rec*40 + seg*8;
        } else { goff[s] = 0; loff[s] = -1; }
    }

    f32x4 acc[4][NT];
#pragma unroll
    for (int mt = 0; mt < 4; ++mt)
#pragma unroll
        for (int nt = 0; nt < NT; ++nt) {
            f32x4 z = {0.f, 0.f, 0.f, 0.f};
            acc[mt][nt] = z;
        }

    int abase[4];
#pragma unroll
    for (int mt = 0; mt < 4; ++mt)
        abase[mt] = ((wv*4 + mt)*20 + nh)*40 + q*8;

    for (int ck = 0; ck < NCHUNK; ++ck) {
        const int c0 = ck*32;
        __syncthreads();
#pragma unroll
        for (int s = 0; s < 7; ++s)
            if (loff[s] >= 0)
                *(bf8*)(&sA[loff[s]]) = *(const bf8*)(&src[goff[s] + c0]);
        __syncthreads();
        const short* wch = wgt + c0 + nh*CPAD + q*8;
        for (int dh = 0; dh < 5; ++dh) {
#pragma unroll
            for (int dw = 0; dw < 5; ++dw) {
                const int tap = dh*5 + dw;
                bf8 bfr[NT];
#pragma unroll
                for (int nt = 0; nt < NT; ++nt)
                    bfr[nt] = *(const bf8*)(&wch[(size_t)(tap*NPAD + nt*16)*CPAD]);
                bf8 afr[4];
#pragma unroll
                for (int mt = 0; mt < 4; ++mt)
                    afr[mt] = *(const bf8*)(&sA[abase[mt] + (dh*20 + dw)*40]);
#pragma unroll
                for (int mt = 0; mt < 4; ++mt)
#pragma unroll
                    for (int nt = 0; nt < NT; ++nt)
                        acc[mt][nt] = __builtin_amdgcn_mfma_f32_16x16x32_bf16(
                            afr[mt], bfr[nt], acc[mt][nt], 0, 0, 0);
            }
        }
    }

    // epilogue: D row (q*4+reg) = position col, D col (nh) = channel
#pragma unroll
    for (int mt = 0; mt < 4; ++mt) {
        const int rowi = h0 + wv*4 + mt;
#pragma unroll
        for (int nt = 0; nt < NT; ++nt) {
            const int chn = nt*16 + nh;
            if (chn < COUT) {
                size_t obase = ((size_t)(b*COUT + chn))*HW_ + rowi*WW + w0 + q*4;
#pragma unroll
                for (int r = 0; r < 4; ++r) {
                    float v = acc[mt][nt][r];
                    if (RELU) v = fmaxf(v, 0.f);
                    if (ADDIN) v += addin[obase + r];
                    out[obase + r] = v;
                }
            }
        }
    }
}

// Depthwise 5x5 surround-modulation conv, ZERO padding. 32x32 tile, TW=4.
__global__ __launch_bounds__(256) void smconv_v2(
    const float* __restrict__ in, const float* __restrict__ sm,
    float* __restrict__ out)
{
    __shared__ __align__(16) float sx[36*36];
    const int tid = threadIdx.x;
    const int tile = blockIdx.x;
    const int e = blockIdx.y;
    const int b = blockIdx.z;
    const int h0 = (tile >> 1) * 32, w0 = (tile & 1) * 32;
    const int r  = tid >> 3;
    const int cg = (tid & 7) * 4;
    const float* inc = in + ((size_t)(b*EXC_ + e))*HW_;
#pragma unroll
    for (int it = 0; it < 6; ++it) {
        int i = tid + it*256;
        if (i < 1296) {
            int lh = i / 36, lw = i - lh*36;
            int gh = h0 - 2 + lh, gw = w0 - 2 + lw;
            float v = 0.f;
            if (gh >= 0 && gh < HH && gw >= 0 && gw < WW) v = inc[gh*WW + gw];
            sx[i] = v;
        }
    }
    __syncthreads();
    float a0 = 0.f, a1 = 0.f, a2 = 0.f, a3 = 0.f;
#pragma unroll
    for (int kh = 0; kh < 5; ++kh) {
        const float4* rowp = (const float4*)(sx + (r + kh)*36 + cg);
        float4 v0 = rowp[0], v1 = rowp[1];
        float xv[8] = {v0.x, v0.y, v0.z, v0.w, v1.x, v1.y, v1.z, v1.w};
#pragma unroll
        for (int kw = 0; kw < 5; ++kw) {
            float wv = sm[kh*5 + kw];
            a0 = fmaf(xv[kw+0], wv, a0);
            a1 = fmaf(xv[kw+1], wv, a1);
            a2 = fmaf(xv[kw+2], wv, a2);
            a3 = fmaf(xv[kw+3], wv, a3);
        }
    }
    size_t oidx = ((size_t)(b*EXC_ + e))*HW_ + (h0 + r)*WW + w0 + cg;
    *(float4*)(out + oidx) = make_float4(a0, a1, a2, a3);
}

// Per-pixel channel argmax (first-occurrence on strict >, matching np.argmax).
__global__ void wta_kernel(const float* __restrict__ in, int* __restrict__ win,
                           float* __restrict__ val, int C, int use_abs)
{
    int p = blockIdx.x*256 + threadIdx.x;   // 0..NPOS-1
    int b = p >> 12, hw = p & 4095;
    const float* base = in + ((size_t)b*C)*HW_ + hw;
    float bestv = base[0];
    float bestk = use_abs ? fabsf(bestv) : bestv;
    int besti = 0;
    for (int c = 1; c < C; ++c) {
        float v = base[(size_t)c*HW_];
        float key = use_abs ? fabsf(v) : v;
        if (key > bestk) { bestk = key; bestv = v; besti = c; }
    }
    win[p] = besti;
    val[p] = bestv;
}

// yx_ee[e,c] = sum_p [win_e==e] val_e * x[b,c,p];  yu_e[e] = sum val_e
__global__ __launch_bounds__(256) void scatter_ee_kernel(
    const float* __restrict__ x, const int* __restrict__ win_e,
    const float* __restrict__ val_e, float* __restrict__ yx_ee,
    float* __restrict__ yu_e)
{
    __shared__ float s_yx[EXC_*CIN_];   // 9792 floats
    __shared__ float s_yu[EXC_];
    for (int i = threadIdx.x; i < EXC_*CIN_; i += 256) s_yx[i] = 0.f;
    if (threadIdx.x < EXC_) s_yu[threadIdx.x] = 0.f;
    __syncthreads();
    int p0 = blockIdx.x * 512;          // 256 blocks x 512 positions
    for (int it = 0; it < 2; ++it) {
        int p = p0 + it*256 + threadIdx.x;
        int b = p >> 12, hw = p & 4095;
        int wi = win_e[p]; float v = val_e[p];
        atomicAdd(&s_yu[wi], v);
        const float* xb = x + ((size_t)b*CIN_)*HW_ + hw;
        float* row = s_yx + wi*CIN_;
        for (int c = 0; c < CIN_; ++c)
            atomicAdd(&row[c], v * xb[(size_t)c*HW_]);
    }
    __syncthreads();
    for (int i = threadIdx.x; i < EXC_*CIN_; i += 256) atomicAdd(&yx_ee[i], s_yx[i]);
    if (threadIdx.x < EXC_) atomicAdd(&yu_e[threadIdx.x], s_yu[threadIdx.x]);
}

// yx_ei[i,e] += val_e*val_i at (win_i,win_e);  yu_i[i] += |val_i|
__global__ __launch_bounds__(256) void scatter_ei_kernel(
    const int* __restrict__ win_e, const float* __restrict__ val_e,
    const int* __restrict__ win_i, const float* __restrict__ val_i,
    float* __restrict__ yx_ei, float* __restrict__ yu_i)
{
    __shared__ float s[INH_*EXC_ + INH_];  // 2652 + 26
    for (int i = threadIdx.x; i < INH_*EXC_ + INH_; i += 256) s[i] = 0.f;
    __syncthreads();
    int p0 = blockIdx.x * 1024;            // 128 blocks x 1024 positions
    for (int it = 0; it < 4; ++it) {
        int p = p0 + it*256 + threadIdx.x;
        int we = win_e[p]; float ve = val_e[p];
        int wi = win_i[p]; float vi = val_i[p];
        atomicAdd(&s[wi*EXC_ + we], ve*vi);
        atomicAdd(&s[INH_*EXC_ + wi], fabsf(vi));
    }
    __syncthreads();
    for (int i = threadIdx.x; i < INH_*EXC_ + INH_; i += 256) {
        float v = s[i];
        if (v != 0.f) {
            if (i < INH_*EXC_) atomicAdd(&yx_ei[i], v);
            else               atomicAdd(&yu_i[i - INH_*EXC_], v);
        }
    }
}

// yx_ie[e,i] = sum_p [win_i==i] val_i * y[b,e,p]
__global__ __launch_bounds__(256) void scatter_ie_kernel(
    const float* __restrict__ y, const int* __restrict__ win_i,
    const float* __restrict__ val_i, float* __restrict__ yx_ie)
{
    __shared__ float s[EXC_*INH_];  // 2652
    for (int i = threadIdx.x; i < EXC_*INH_; i += 256) s[i] = 0.f;
    __syncthreads();
    int p0 = blockIdx.x * 512;      // 256 blocks x 512 positions
    for (int it = 0; it < 2; ++it) {
        int p = p0 + it*256 + threadIdx.x;
        int b = p >> 12, hw = p & 4095;
        int wi = win_i[p]; float v = val_i[p];
        if (v != 0.f) {
            const float* yb = y + ((size_t)b*EXC_)*HW_ + hw;
            for (int e = 0; e < EXC_; ++e)
                atomicAdd(&s[e*INH_ + wi], v * yb[(size_t)e*HW_]);
        }
    }
    __syncthreads();
    for (int i = threadIdx.x; i < EXC_*INH_; i += 256) atomicAdd(&yx_ie[i], s[i]);
}

// absmax of upd = yx - yu[e]*w  (nonneg float bits are int-monotonic)
__global__ void upd_absmax_kernel(const float* __restrict__ yx,
    const float* __restrict__ yu, const float* __restrict__ w,
    int E, int C, unsigned int* __restrict__ amax)
{
    __shared__ unsigned int sm_;
    if (threadIdx.x == 0) sm_ = 0u;
    __syncthreads();
    int n = E*C*25;
    float m = 0.f;
    for (int idx = blockIdx.x*256 + threadIdx.x; idx < n; idx += gridDim.x*256) {
        int ec = idx / 25;
        int e = ec / C;
        float v = yx[ec] - yu[e]*w[idx];
        m = fmaxf(m, fabsf(v));
    }
    atomicMax(&sm_, __float_as_uint(m));
    __syncthreads();
    if (threadIdx.x == 0) atomicMax(amax, sm_);
}

__global__ void upd_write_kernel(const float* __restrict__ yx,
    const float* __restrict__ yu, const float* __restrict__ w,
    int E, int C, const unsigned int* __restrict__ amax,
    float* __restrict__ out)
{
    int n = E*C*25;
    int idx = blockIdx.x*256 + threadIdx.x;
    if (idx >= n) return;
    int ec = idx / 25;
    int e = ec / C;
    float v = yx[ec] - yu[e]*w[idx];
    float mx = __uint_as_float(*amax);
    out[idx] = v / (mx + 1e-8f);
}

extern "C" void kernel_launch(void* const* d_in, const int* in_sizes, int n_in,
                              void* d_out, int out_size, void* d_ws, size_t ws_size,
                              hipStream_t stream)
{
    const float* x    = (const float*)d_in[0];
    const float* w_ee = (const float*)d_in[1];
    const float* w_ei = (const float*)d_in[2];
    const float* w_ie = (const float*)d_in[3];
    const float* smk  = (const float*)d_in[4];
    float* out = (float*)d_out;

    // ---- workspace layout ----
    float* y_e = (float*)d_ws;                           // 13,369,344 f (53.5 MB)
    float* y_i = y_e + (size_t)B_*EXC_*HW_;              //  3,407,872 f (13.6 MB)
    // R: shared region reused in sequence: xbf (25.2MB) -> yebf (33.6MB) -> yibf (8.4MB)
    short* R   = (short*)(y_i + (size_t)B_*INH_*HW_);    // 16,777,216 sh (33.6 MB)
    short* wee = R + (size_t)16777216;                   // 268,800 sh
    short* wei = wee + 268800;                           // 102,400 sh
    short* wie = wei + 102400;                           //  89,600 sh
    int*   win_e = (int*)(wie + 89600);
    float* val_e = (float*)(win_e + NPOS);
    int*   win_i = (int*)(val_e + NPOS);
    float* val_i = (float*)(win_i + NPOS);
    float* yx_ee = val_i + NPOS;                         // 9792
    float* yx_ei = yx_ee + EXC_*CIN_;                    // 2652
    float* yx_ie = yx_ei + INH_*EXC_;                    // 2652
    float* yu_e  = yx_ie + EXC_*INH_;                    // 102
    float* yu_i  = yu_e + EXC_;                          // 26
    unsigned int* amax = (unsigned int*)(yu_i + INH_);   // 3

    hipMemsetAsync(yx_ee, 0,
        (size_t)(EXC_*CIN_ + INH_*EXC_ + EXC_*INH_ + EXC_ + INH_ + 3)*sizeof(float),
        stream);

    // ---- pack weights + input ----
    pack_w<EXC_, CIN_, 112, 96><<<(25*112*96 + 255)/256, 256, 0, stream>>>(w_ee, wee);
    pack_w<INH_, EXC_, 32, 128><<<(25*32*128 + 255)/256, 256, 0, stream>>>(w_ei, wei);
    pack_w<EXC_, INH_, 112, 32><<<(25*112*32 + 255)/256, 256, 0, stream>>>(w_ie, wie);
    pack_nhwc<CIN_, 96><<<dim3(64, 1, B_), 256, 0, stream>>>(x, R);

    // ---- conv1: y_e = conv(x, w_ee) ----
    conv_mfma<96, 112, 7, EXC_, 3, false, false>
        <<<dim3(16, 1, B_), 256, 0, stream>>>(R, wee, nullptr, y_e);
    wta_kernel<<<NPOS/256, 256, 0, stream>>>(y_e, win_e, val_e, EXC_, 0);

    // ---- conv2: y_i = relu(conv(y_e, w_ei)) ----
    pack_nhwc<EXC_, 128><<<dim3(64, 1, B_), 256, 0, stream>>>(y_e, R);
    conv_mfma<128, 32, 2, INH_, 4, true, false>
        <<<dim3(16, 1, B_), 256, 0, stream>>>(R, wei, nullptr, y_i);
    wta_kernel<<<NPOS/256, 256, 0, stream>>>(y_i, win_i, val_i, INH_, 1);

    // ---- conv3: y_pre = y_e + conv(y_i, w_ie)  (in place over y_e) ----
    pack_nhwc<INH_, 32><<<dim3(64, 1, B_), 256, 0, stream>>>(y_i, R);
    conv_mfma<32, 112, 7, EXC_, 1, false, true>
        <<<dim3(16, 1, B_), 256, 0, stream>>>(R, wie, y_e, y_e);

    // ---- y = depthwise sm conv (zero pad) -> d_out chunk 0 ----
    smconv_v2<<<dim3(4, EXC_, B_), 256, 0, stream>>>(y_e, smk, out);

    // ---- Hebbian scatters ----
    scatter_ee_kernel<<<256, 256, 0, stream>>>(x, win_e, val_e, yx_ee, yu_e);
    scatter_ei_kernel<<<128, 256, 0, stream>>>(win_e, val_e, win_i, val_i, yx_ei, yu_i);
    scatter_ie_kernel<<<256, 256, 0, stream>>>(out, win_i, val_i, yx_ie);

    // ---- upd normalization ----
    upd_absmax_kernel<<<240, 256, 0, stream>>>(yx_ee, yu_e, w_ee, EXC_, CIN_, amax+0);
    upd_absmax_kernel<<<240, 256, 0, stream>>>(yx_ei, yu_i, w_ei, INH_, EXC_, amax+1);
    upd_absmax_kernel<<<240, 256, 0, stream>>>(yx_ie, yu_e, w_ie, EXC_, INH_, amax+2);

    float* out_ee = out + (size_t)B_*EXC_*HW_;
    float* out_ei = out_ee + EXC_*CIN_*25;
    float* out_ie = out_ei + INH_*EXC_*25;
    upd_write_kernel<<<(EXC_*CIN_*25+255)/256, 256, 0, stream>>>(yx_ee, yu_e, w_ee, EXC_, CIN_, amax+0, out_ee);
    upd_write_kernel<<<(INH_*EXC_*25+255)/256, 256, 0, stream>>>(yx_ei, yu_i, w_ei, INH_, EXC_, amax+1, out_ei);
    upd_write_kernel<<<(EXC_*INH_*25+255)/256, 256, 0, stream>>>(yx_ie, yu_e, w_ie, EXC_, INH_, amax+2, out_ie);
}